// Round 1
// baseline (332.634 us; speedup 1.0000x reference)
//
#include <hip/hip_runtime.h>

// Problem constants: VOCAB=100000, EMB=300, B=2048, L=200, H=128, OUT=20
#define VOCAB 100000
#define BB   2048
#define LL   200
#define EMB  300
#define HH   128
#define OUTD 20
#define NSRT 256        // bitonic sort width (LL padded with INT_MAX)
#define RPW  (LL / 4)   // 50 rows per wave (legacy fallback kernel)

// =====================================================================
// Kernel 1: P = table @ W1   (fp32 tiled GEMM, 100000x300 @ 300x128)
// Rationale: network is linear up to the first relu, so project the
// embedding table through W1 ONCE (compute-bound, ~49 us ideal) and
// gather 512 B rows instead of 1200 B -> random-read traffic 491->210 MB.
// =====================================================================
#define BMp 128
#define BKp 64
#define KSTEPS 5   // ceil(300/64); staging zero-fills k>=300

__global__ __launch_bounds__(256) void proj_gemm(
    const float* __restrict__ table,   // [VOCAB, EMB]
    const float* __restrict__ W1,      // [EMB, HH]
    float*       __restrict__ P)       // [VOCAB, HH]
{
    __shared__ float A_s[BKp][BMp + 4];   // [k][row], +4 pad: conflict-free reads
    __shared__ float B_s[BKp][HH + 4];    // [k][col]

    const int t    = threadIdx.x;
    const int tx   = t & 15;              // output col group (8 cols)
    const int ty   = t >> 4;              // output row group (8 rows)
    const int row0 = blockIdx.x * BMp;

    float acc[8][8];
    #pragma unroll
    for (int i = 0; i < 8; ++i)
        #pragma unroll
        for (int j = 0; j < 8; ++j) acc[i][j] = 0.f;

    for (int ks = 0; ks < KSTEPS; ++ks) {
        const int kbase = ks * BKp;

        // ---- stage A (transposed to [k][row]): thread t covers row t>>1,
        // float4 chunks (t&1)*8 .. +7 along k. 2-way LDS write alias = free.
        {
            const int ar  = t >> 1;
            const int row = row0 + ar;
            const int cq0 = (t & 1) * 8;
            #pragma unroll
            for (int i = 0; i < 8; ++i) {
                const int kk = (cq0 + i) << 2;     // 0..60
                const int k  = kbase + kk;
                float4 v = make_float4(0.f, 0.f, 0.f, 0.f);
                if (row < VOCAB && k < EMB)        // k multiple of 4; 300%4==0 so no partial float4
                    v = *(const float4*)(table + (size_t)row * EMB + k);
                A_s[kk + 0][ar] = v.x;
                A_s[kk + 1][ar] = v.y;
                A_s[kk + 2][ar] = v.z;
                A_s[kk + 3][ar] = v.w;
            }
        }
        // ---- stage B: thread t covers k-row t>>2, float4 chunks (t&3)*8 .. +7
        {
            const int kr = t >> 2;
            const int k  = kbase + kr;
            const int c0 = (t & 3) * 32;
            #pragma unroll
            for (int i = 0; i < 8; ++i) {
                float4 v = make_float4(0.f, 0.f, 0.f, 0.f);
                if (k < EMB)
                    v = *(const float4*)(W1 + (size_t)k * HH + c0 + (i << 2));
                *(float4*)&B_s[kr][c0 + (i << 2)] = v;
            }
        }
        __syncthreads();

        // ---- 8x8 micro-tile: per k-iter 4x ds_read_b128 + 64 FMA (VALU-bound)
        #pragma unroll 4
        for (int k = 0; k < BKp; ++k) {
            const float4 a0  = *(const float4*)&A_s[k][ty * 8];
            const float4 a1  = *(const float4*)&A_s[k][ty * 8 + 4];
            const float4 b0  = *(const float4*)&B_s[k][tx * 8];
            const float4 b1v = *(const float4*)&B_s[k][tx * 8 + 4];
            const float a[8]  = {a0.x, a0.y, a0.z, a0.w, a1.x, a1.y, a1.z, a1.w};
            const float bb[8] = {b0.x, b0.y, b0.z, b0.w, b1v.x, b1v.y, b1v.z, b1v.w};
            #pragma unroll
            for (int i = 0; i < 8; ++i)
                #pragma unroll
                for (int j = 0; j < 8; ++j)
                    acc[i][j] = fmaf(a[i], bb[j], acc[i][j]);
        }
        __syncthreads();
    }

    #pragma unroll
    for (int i = 0; i < 8; ++i) {
        const int row = row0 + ty * 8 + i;
        if (row < VOCAB) {
            const float4 o0 = make_float4(acc[i][0], acc[i][1], acc[i][2], acc[i][3]);
            const float4 o1 = make_float4(acc[i][4], acc[i][5], acc[i][6], acc[i][7]);
            *(float4*)(P + (size_t)row * HH + tx * 8)     = o0;
            *(float4*)(P + (size_t)row * HH + tx * 8 + 4) = o1;
        }
    }
}

// =====================================================================
// Kernel 2: gather-sum over P (512 B rows) + tiny MLP epilogue.
// One block per sample, 4 waves. Rows are bitonic-sorted (ascending vocab
// sweep -> L3 band locality, proven in prior session). A full wave load
// (64 x float4 = 1024 B) now covers exactly TWO rows: lanes 0-31 row 2i,
// lanes 32-63 row 2i+1 -> zero tail waste, 25 vmem instr per wave.
// =====================================================================
__global__ __launch_bounds__(256) void gather_mlp(
    const int*   __restrict__ x,        // [B, L]
    const int*   __restrict__ lengths,  // [B]
    const float* __restrict__ P,        // [VOCAB, HH]
    const float* __restrict__ b1,       // [HH]
    const float* __restrict__ W2,       // [HH, OUT]
    const float* __restrict__ b2,       // [OUT]
    float*       __restrict__ out)      // [B, OUT]
{
    __shared__ int   idx_s[NSRT];
    __shared__ float part_f[4][256];    // [wave][half*128 + col]
    __shared__ float h_s[HH];

    const int b    = blockIdx.x;
    const int t    = threadIdx.x;
    const int w    = t >> 6;
    const int lane = t & 63;

    idx_s[t] = (t < LL) ? x[b * LL + t] : 0x7FFFFFFF;
    __syncthreads();

    // ---- bitonic sort ascending over 256 slots
    #pragma unroll
    for (int k = 2; k <= NSRT; k <<= 1) {
        #pragma unroll
        for (int j = k >> 1; j > 0; j >>= 1) {
            const int ixj = t ^ j;
            if (ixj > t) {
                const int a0 = idx_s[t];
                const int a1 = idx_s[ixj];
                const bool up = ((t & k) == 0);
                if ((a0 > a1) == up) { idx_s[t] = a1; idx_s[ixj] = a0; }
            }
            __syncthreads();
        }
    }

    // lane j holds this wave's j-th row index (wave-interleaved over sorted order)
    const int myidx = (lane < RPW) ? idx_s[w + 4 * lane] : 0;

    // ---- gather-sum: two rows per full-wave dwordx4 load
    float4 acc = make_float4(0.f, 0.f, 0.f, 0.f);
    #pragma unroll 5
    for (int i = 0; i < RPW / 2; ++i) {                       // 25 iterations
        const int r0 = __builtin_amdgcn_readlane(myidx, 2 * i);
        const int r1 = __builtin_amdgcn_readlane(myidx, 2 * i + 1);
        const int ridx = (lane < 32) ? r0 : r1;
        const float4 v = ((const float4*)(P + (size_t)ridx * HH))[lane & 31];
        acc.x += v.x; acc.y += v.y; acc.z += v.z; acc.w += v.w;
    }
    // lane l holds partial of cols (l&31)*4..+3, half = l>>5  -> offset half*128+col
    *(float4*)&part_f[w][lane << 2] = acc;
    __syncthreads();

    // ---- reduce 8 partials per col, scale, +b1, relu
    const float inv_len = 1.0f / (float)lengths[b];
    if (t < HH) {
        float s = 0.f;
        #pragma unroll
        for (int ww = 0; ww < 4; ++ww)
            s += part_f[ww][t] + part_f[ww][128 + t];
        h_s[t] = fmaxf(fmaf(s, inv_len, b1[t]), 0.f);
    }
    __syncthreads();

    // ---- logits = h @ W2 + b2
    if (t < OUTD) {
        float o = b2[t];
        #pragma unroll
        for (int k = 0; k < HH; ++k)
            o = fmaf(h_s[k], W2[k * OUTD + t], o);
        out[b * OUTD + t] = o;
    }
}

// =====================================================================
// Fallback: prior session's proven fused kernel (241.6 us) — used only
// if the workspace is too small for P.
// =====================================================================
__global__ __launch_bounds__(256) void fused_dnn(
    const int*   __restrict__ x,
    const int*   __restrict__ lengths,
    const float* __restrict__ table,
    const float* __restrict__ W1,
    const float* __restrict__ b1,
    const float* __restrict__ W2,
    const float* __restrict__ b2,
    float*       __restrict__ out)
{
    __shared__ int    idx_s[NSRT];
    __shared__ float4 part_s[4][76];
    __shared__ float  rep_s[EMB];
    __shared__ float  h_part[2][HH];
    __shared__ float  h_s[HH];

    const int b    = blockIdx.x;
    const int t    = threadIdx.x;
    const int w    = t >> 6;
    const int lane = t & 63;

    idx_s[t] = (t < LL) ? x[b * LL + t] : 0x7FFFFFFF;
    __syncthreads();

    #pragma unroll
    for (int k = 2; k <= NSRT; k <<= 1) {
        #pragma unroll
        for (int j = k >> 1; j > 0; j >>= 1) {
            const int ixj = t ^ j;
            if (ixj > t) {
                const int a0 = idx_s[t];
                const int a1 = idx_s[ixj];
                const bool up = ((t & k) == 0);
                if ((a0 > a1) == up) { idx_s[t] = a1; idx_s[ixj] = a0; }
            }
            __syncthreads();
        }
    }

    const int myidx = (lane < RPW) ? idx_s[w + 4 * lane] : 0;

    float4 acc_a = make_float4(0.f, 0.f, 0.f, 0.f);
    float4 acc_b = make_float4(0.f, 0.f, 0.f, 0.f);
    const bool hasb = (lane < (EMB / 4 - 64));

    #pragma unroll 5
    for (int i = 0; i < RPW; ++i) {
        const int ridx = __builtin_amdgcn_readlane(myidx, i);
        const float4* row = (const float4*)(table + (size_t)ridx * EMB);
        float4 va = row[lane];
        acc_a.x += va.x; acc_a.y += va.y; acc_a.z += va.z; acc_a.w += va.w;
        if (hasb) {
            float4 vb = row[64 + lane];
            acc_b.x += vb.x; acc_b.y += vb.y; acc_b.z += vb.z; acc_b.w += vb.w;
        }
    }

    part_s[w][lane] = acc_a;
    if (hasb) part_s[w][64 + lane] = acc_b;
    __syncthreads();

    const float inv_len = 1.0f / (float)lengths[b];
    const float* ps = (const float*)part_s;
    {
        float s = ps[t] + ps[304 + t] + ps[608 + t] + ps[912 + t];
        rep_s[t] = s * inv_len;
    }
    if (t < (EMB - 256)) {
        int c = 256 + t;
        float s = ps[c] + ps[304 + c] + ps[608 + c] + ps[912 + c];
        rep_s[c] = s * inv_len;
    }
    __syncthreads();

    {
        const int half = t >> 7;
        const int col  = t & 127;
        float hacc = (half == 0) ? b1[col] : 0.0f;
        const int k0 = half * (EMB / 2);
        #pragma unroll 5
        for (int k = k0; k < k0 + EMB / 2; ++k)
            hacc = fmaf(rep_s[k], W1[k * HH + col], hacc);
        h_part[half][col] = hacc;
    }
    __syncthreads();
    if (t < HH)
        h_s[t] = fmaxf(h_part[0][t] + h_part[1][t], 0.0f);
    __syncthreads();

    if (t < OUTD) {
        float oacc = b2[t];
        #pragma unroll
        for (int k = 0; k < HH; ++k)
            oacc = fmaf(h_s[k], W2[k * OUTD + t], oacc);
        out[b * OUTD + t] = oacc;
    }
}

extern "C" void kernel_launch(void* const* d_in, const int* in_sizes, int n_in,
                              void* d_out, int out_size, void* d_ws, size_t ws_size,
                              hipStream_t stream) {
    const int*   x       = (const int*)  d_in[0];
    const int*   lengths = (const int*)  d_in[1];
    const float* table   = (const float*)d_in[2];
    const float* W1      = (const float*)d_in[3];
    const float* b1      = (const float*)d_in[4];
    const float* W2      = (const float*)d_in[5];
    const float* b2      = (const float*)d_in[6];
    float*       out     = (float*)d_out;

    const size_t PBYTES = (size_t)VOCAB * HH * sizeof(float);   // 51.2 MB

    if (d_ws != nullptr && ws_size >= PBYTES) {
        float* P = (float*)d_ws;
        const int mtiles = (VOCAB + BMp - 1) / BMp;             // 782
        proj_gemm<<<mtiles, 256, 0, stream>>>(table, W1, P);
        gather_mlp<<<BB, 256, 0, stream>>>(x, lengths, P, b1, W2, b2, out);
    } else {
        fused_dnn<<<BB, 256, 0, stream>>>(x, lengths, table, W1, b1, W2, b2, out);
    }
}

// Round 2
// 308.076 us; speedup vs baseline: 1.0797x; 1.0797x over previous
//
#include <hip/hip_runtime.h>

// Problem constants: VOCAB=100000, EMB=300, B=2048, L=200, H=128, OUT=20
#define VOCAB 100000
#define BB   2048
#define LL   200
#define EMB  300
#define HH   128
#define OUTD 20
#define NSRT 256        // bitonic sort width (LL padded with INT_MAX)
#define RPW  (LL / 4)   // 50 rows per wave

// =====================================================================
// Kernel 1: P = table @ W1   (fp32 tiled GEMM, 100000x300 @ 300x128)
// v2: BK=32 (LDS 34.5KB -> 4 blocks/CU, 16 waves/CU, all 782 blocks
// resident in one round) + swizzled B_s layout (float4 index q -> q+(q>>3),
// row stride 144) so the 16-address stride-32B B reads go from 4-way bank
// conflict (banks {0,8,16,24}) to 2-way (free). Post-fix the VALU pipe is
// the binding resource: LDS/CU ~448 cyc vs VALU/SIMD 512 cyc per k-iter.
// =====================================================================
#define BMp 128
#define BKp 32
#define KSTEPS 10   // ceil(300/32); staging zero-fills k>=300
#define BSW 144     // swizzled B row stride (max offset 139)

__global__ __launch_bounds__(256, 4) void proj_gemm(
    const float* __restrict__ table,   // [VOCAB, EMB]
    const float* __restrict__ W1,      // [EMB, HH]
    float*       __restrict__ P)       // [VOCAB, HH]
{
    __shared__ float A_s[BKp][BMp + 4];   // [k][row] transposed; write banks 2-way
    __shared__ float B_s[BKp][BSW];       // [k][swizzled col]

    const int t    = threadIdx.x;
    const int tx   = t & 15;              // output col group (8 cols)
    const int ty   = t >> 4;              // output row group (8 rows)
    const int row0 = blockIdx.x * BMp;

    // swizzled read base: float4 chunk q=2*tx -> q' = q + (q>>3)
    const int bswz = 8 * tx + 4 * (tx >> 2);

    float acc[8][8];
    #pragma unroll
    for (int i = 0; i < 8; ++i)
        #pragma unroll
        for (int j = 0; j < 8; ++j) acc[i][j] = 0.f;

    for (int ks = 0; ks < KSTEPS; ++ks) {
        const int kbase = ks * BKp;

        // ---- stage A (transposed to [k][row]): thread t covers row t>>1,
        // float4 chunks along k at k=(t&1)*16+4i. Write banks: 2-way (free).
        {
            const int ar  = t >> 1;
            const int row = row0 + ar;
            const int kc  = (t & 1) * 16;
            #pragma unroll
            for (int i = 0; i < 4; ++i) {
                const int kk = kc + 4 * i;
                const int k  = kbase + kk;
                float4 v = make_float4(0.f, 0.f, 0.f, 0.f);
                if (row < VOCAB && k < EMB)        // 300%4==0: float4 all-or-nothing
                    v = *(const float4*)(table + (size_t)row * EMB + k);
                A_s[kk + 0][ar] = v.x;
                A_s[kk + 1][ar] = v.y;
                A_s[kk + 2][ar] = v.z;
                A_s[kk + 3][ar] = v.w;
            }
        }
        // ---- stage B swizzled: thread t covers k-row t>>3, cols (t&7)*16+4i.
        // q = (t&7)*4+i never crosses an 8-boundary within a float4 -> b128 ok.
        {
            const int kr = t >> 3;
            const int k  = kbase + kr;
            const int m  = t & 7;
            #pragma unroll
            for (int i = 0; i < 4; ++i) {
                const int c = m * 16 + 4 * i;
                float4 v = make_float4(0.f, 0.f, 0.f, 0.f);
                if (k < EMB)
                    v = *(const float4*)(W1 + (size_t)k * HH + c);
                const int q = m * 4 + i;
                *(float4*)&B_s[kr][4 * q + 4 * (q >> 3)] = v;
            }
        }
        __syncthreads();

        // ---- 8x8 micro-tile: per k-iter 2 broadcast A reads (conflict-free)
        // + 2 swizzled B reads (2-way max) + 64 FMA
        #pragma unroll 4
        for (int k = 0; k < BKp; ++k) {
            const float4 a0  = *(const float4*)&A_s[k][ty * 8];
            const float4 a1  = *(const float4*)&A_s[k][ty * 8 + 4];
            const float4 b0  = *(const float4*)&B_s[k][bswz];
            const float4 b1v = *(const float4*)&B_s[k][bswz + 4];
            const float a[8]  = {a0.x, a0.y, a0.z, a0.w, a1.x, a1.y, a1.z, a1.w};
            const float bb[8] = {b0.x, b0.y, b0.z, b0.w, b1v.x, b1v.y, b1v.z, b1v.w};
            #pragma unroll
            for (int i = 0; i < 8; ++i)
                #pragma unroll
                for (int j = 0; j < 8; ++j)
                    acc[i][j] = fmaf(a[i], bb[j], acc[i][j]);
        }
        __syncthreads();
    }

    #pragma unroll
    for (int i = 0; i < 8; ++i) {
        const int row = row0 + ty * 8 + i;
        if (row < VOCAB) {
            const float4 o0 = make_float4(acc[i][0], acc[i][1], acc[i][2], acc[i][3]);
            const float4 o1 = make_float4(acc[i][4], acc[i][5], acc[i][6], acc[i][7]);
            *(float4*)(P + (size_t)row * HH + tx * 8)     = o0;
            *(float4*)(P + (size_t)row * HH + tx * 8 + 4) = o1;
        }
    }
}

// =====================================================================
// Kernel 2: gather-sum over P (512 B rows) + tiny MLP epilogue.
// UNCHANGED from round 1 (isolating the proj change). Its counters will
// surface in top-5 this round now that proj shrinks -> round-3 decision:
// hbm_bytes ~210MB => HBM-bound (go bf16 P); hbm_bytes small => L3
// latency-bound (attack MLP/structure).
// =====================================================================
__global__ __launch_bounds__(256) void gather_mlp(
    const int*   __restrict__ x,        // [B, L]
    const int*   __restrict__ lengths,  // [B]
    const float* __restrict__ P,        // [VOCAB, HH]
    const float* __restrict__ b1,       // [HH]
    const float* __restrict__ W2,       // [HH, OUT]
    const float* __restrict__ b2,       // [OUT]
    float*       __restrict__ out)      // [B, OUT]
{
    __shared__ int   idx_s[NSRT];
    __shared__ float part_f[4][256];    // [wave][half*128 + col]
    __shared__ float h_s[HH];

    const int b    = blockIdx.x;
    const int t    = threadIdx.x;
    const int w    = t >> 6;
    const int lane = t & 63;

    idx_s[t] = (t < LL) ? x[b * LL + t] : 0x7FFFFFFF;
    __syncthreads();

    // ---- bitonic sort ascending over 256 slots
    #pragma unroll
    for (int k = 2; k <= NSRT; k <<= 1) {
        #pragma unroll
        for (int j = k >> 1; j > 0; j >>= 1) {
            const int ixj = t ^ j;
            if (ixj > t) {
                const int a0 = idx_s[t];
                const int a1 = idx_s[ixj];
                const bool up = ((t & k) == 0);
                if ((a0 > a1) == up) { idx_s[t] = a1; idx_s[ixj] = a0; }
            }
            __syncthreads();
        }
    }

    // lane j holds this wave's j-th row index (wave-interleaved over sorted order)
    const int myidx = (lane < RPW) ? idx_s[w + 4 * lane] : 0;

    // ---- gather-sum: two rows per full-wave dwordx4 load
    float4 acc = make_float4(0.f, 0.f, 0.f, 0.f);
    #pragma unroll 5
    for (int i = 0; i < RPW / 2; ++i) {                       // 25 iterations
        const int r0 = __builtin_amdgcn_readlane(myidx, 2 * i);
        const int r1 = __builtin_amdgcn_readlane(myidx, 2 * i + 1);
        const int ridx = (lane < 32) ? r0 : r1;
        const float4 v = ((const float4*)(P + (size_t)ridx * HH))[lane & 31];
        acc.x += v.x; acc.y += v.y; acc.z += v.z; acc.w += v.w;
    }
    // lane l holds partial of cols (l&31)*4..+3, half = l>>5  -> offset half*128+col
    *(float4*)&part_f[w][lane << 2] = acc;
    __syncthreads();

    // ---- reduce 8 partials per col, scale, +b1, relu
    const float inv_len = 1.0f / (float)lengths[b];
    if (t < HH) {
        float s = 0.f;
        #pragma unroll
        for (int ww = 0; ww < 4; ++ww)
            s += part_f[ww][t] + part_f[ww][128 + t];
        h_s[t] = fmaxf(fmaf(s, inv_len, b1[t]), 0.f);
    }
    __syncthreads();

    // ---- logits = h @ W2 + b2
    if (t < OUTD) {
        float o = b2[t];
        #pragma unroll
        for (int k = 0; k < HH; ++k)
            o = fmaf(h_s[k], W2[k * OUTD + t], o);
        out[b * OUTD + t] = o;
    }
}

// =====================================================================
// Fallback: prior session's proven fused kernel — used only if the
// workspace is too small for P.
// =====================================================================
__global__ __launch_bounds__(256) void fused_dnn(
    const int*   __restrict__ x,
    const int*   __restrict__ lengths,
    const float* __restrict__ table,
    const float* __restrict__ W1,
    const float* __restrict__ b1,
    const float* __restrict__ W2,
    const float* __restrict__ b2,
    float*       __restrict__ out)
{
    __shared__ int    idx_s[NSRT];
    __shared__ float4 part_s[4][76];
    __shared__ float  rep_s[EMB];
    __shared__ float  h_part[2][HH];
    __shared__ float  h_s[HH];

    const int b    = blockIdx.x;
    const int t    = threadIdx.x;
    const int w    = t >> 6;
    const int lane = t & 63;

    idx_s[t] = (t < LL) ? x[b * LL + t] : 0x7FFFFFFF;
    __syncthreads();

    #pragma unroll
    for (int k = 2; k <= NSRT; k <<= 1) {
        #pragma unroll
        for (int j = k >> 1; j > 0; j >>= 1) {
            const int ixj = t ^ j;
            if (ixj > t) {
                const int a0 = idx_s[t];
                const int a1 = idx_s[ixj];
                const bool up = ((t & k) == 0);
                if ((a0 > a1) == up) { idx_s[t] = a1; idx_s[ixj] = a0; }
            }
            __syncthreads();
        }
    }

    const int myidx = (lane < RPW) ? idx_s[w + 4 * lane] : 0;

    float4 acc_a = make_float4(0.f, 0.f, 0.f, 0.f);
    float4 acc_b = make_float4(0.f, 0.f, 0.f, 0.f);
    const bool hasb = (lane < (EMB / 4 - 64));

    #pragma unroll 5
    for (int i = 0; i < RPW; ++i) {
        const int ridx = __builtin_amdgcn_readlane(myidx, i);
        const float4* row = (const float4*)(table + (size_t)ridx * EMB);
        float4 va = row[lane];
        acc_a.x += va.x; acc_a.y += va.y; acc_a.z += va.z; acc_a.w += va.w;
        if (hasb) {
            float4 vb = row[64 + lane];
            acc_b.x += vb.x; acc_b.y += vb.y; acc_b.z += vb.z; acc_b.w += vb.w;
        }
    }

    part_s[w][lane] = acc_a;
    if (hasb) part_s[w][64 + lane] = acc_b;
    __syncthreads();

    const float inv_len = 1.0f / (float)lengths[b];
    const float* ps = (const float*)part_s;
    {
        float s = ps[t] + ps[304 + t] + ps[608 + t] + ps[912 + t];
        rep_s[t] = s * inv_len;
    }
    if (t < (EMB - 256)) {
        int c = 256 + t;
        float s = ps[c] + ps[304 + c] + ps[608 + c] + ps[912 + c];
        rep_s[c] = s * inv_len;
    }
    __syncthreads();

    {
        const int half = t >> 7;
        const int col  = t & 127;
        float hacc = (half == 0) ? b1[col] : 0.0f;
        const int k0 = half * (EMB / 2);
        #pragma unroll 5
        for (int k = k0; k < k0 + EMB / 2; ++k)
            hacc = fmaf(rep_s[k], W1[k * HH + col], hacc);
        h_part[half][col] = hacc;
    }
    __syncthreads();
    if (t < HH)
        h_s[t] = fmaxf(h_part[0][t] + h_part[1][t], 0.0f);
    __syncthreads();

    if (t < OUTD) {
        float oacc = b2[t];
        #pragma unroll
        for (int k = 0; k < HH; ++k)
            oacc = fmaf(h_s[k], W2[k * OUTD + t], oacc);
        out[b * OUTD + t] = oacc;
    }
}

extern "C" void kernel_launch(void* const* d_in, const int* in_sizes, int n_in,
                              void* d_out, int out_size, void* d_ws, size_t ws_size,
                              hipStream_t stream) {
    const int*   x       = (const int*)  d_in[0];
    const int*   lengths = (const int*)  d_in[1];
    const float* table   = (const float*)d_in[2];
    const float* W1      = (const float*)d_in[3];
    const float* b1      = (const float*)d_in[4];
    const float* W2      = (const float*)d_in[5];
    const float* b2      = (const float*)d_in[6];
    float*       out     = (float*)d_out;

    const size_t PBYTES = (size_t)VOCAB * HH * sizeof(float);   // 51.2 MB

    if (d_ws != nullptr && ws_size >= PBYTES) {
        float* P = (float*)d_ws;
        const int mtiles = (VOCAB + BMp - 1) / BMp;             // 782
        proj_gemm<<<mtiles, 256, 0, stream>>>(table, W1, P);
        gather_mlp<<<BB, 256, 0, stream>>>(x, lengths, P, b1, W2, b2, out);
    } else {
        fused_dnn<<<BB, 256, 0, stream>>>(x, lengths, table, W1, b1, W2, b2, out);
    }
}